// Round 15
// baseline (713.024 us; speedup 1.0000x reference)
//
#include <hip/hip_runtime.h>
#include <hip/hip_bf16.h>

#define NU 100000
#define NM 20000
#define DD 64
#define RR 5
#define EE 400000
#define NE (RR * EE)            // 2,000,000 edges per direction
#define NNODE (NM + NU)         // 120,000 destination bins (movies first)
#define NTILE (EE / 16)         // 25,000 16-edge tiles per relation
#define NCHUNK ((NNODE + 1023) / 1024)   // 118 scan chunks
#define GM_BLOCKS (NM / 4)      // 5000 movie-gather blocks (4 movies/block)
#define GU_BLOCKS (NU / 32)     // 3125 user-gather blocks (32 users/block)

typedef __attribute__((ext_vector_type(8))) short bf16x8;
typedef __attribute__((ext_vector_type(8))) short s16x8;
typedef __attribute__((ext_vector_type(4))) int   i32x4;
typedef __attribute__((ext_vector_type(4))) float f32x4;

static __device__ __forceinline__ short f2bf(float f) {
  return __builtin_bit_cast(short, __float2bfloat16(f));
}
static __device__ __forceinline__ float bf2f(short s) {
  return __builtin_bit_cast(float, ((unsigned)(unsigned short)s) << 16);
}

// nt LOAD of host-written, read-once input only (rfeat). R14 lesson: nt
// STORES consumed by a later kernel corrupt data on gfx950 (per-XCD L2 +
// no-allocate path) — never again. nt loads of pure inputs are safe.
static __device__ __forceinline__ f32x4 ntl_f4(const float* __restrict__ p) {
  return __builtin_nontemporal_load((const f32x4*)p);
}

static __device__ __forceinline__ bf16x8 pack8e(const f32x4 a, const f32x4 b) {
  bf16x8 o;
  o[0] = f2bf(a.x); o[1] = f2bf(a.y); o[2] = f2bf(a.z); o[3] = f2bf(a.w);
  o[4] = f2bf(b.x); o[5] = f2bf(b.y); o[6] = f2bf(b.z); o[7] = f2bf(b.w);
  return o;
}
static __device__ __forceinline__ bf16x8 cvt8(const float* __restrict__ p) {
  return pack8e(*(const f32x4*)p, *(const f32x4*)(p + 4));
}

static __device__ __forceinline__ float sigm(float x) { return 1.f / (1.f + __expf(-x)); }
static __device__ __forceinline__ float gelu(float x) {
  return 0.5f * x * (1.f + erff(x * 0.70710678118654752f));
}

// ---------------------------------------------------------------------------
// rank0: ONE atomic pass. cnt (zeroed) -> per-edge rank within destination,
// and cnt ends up holding the per-node degree (input to the scan).
// ---------------------------------------------------------------------------
__global__ __launch_bounds__(256) void rank0_k(const int* __restrict__ eu,
                                               const int* __restrict__ em,
                                               int* __restrict__ cnt,
                                               int* __restrict__ rank_m,
                                               int* __restrict__ rank_u) {
  const int i = (blockIdx.x * 256 + threadIdx.x) * 4;
  if (i < NE) {
    const i32x4 a = *(const i32x4*)(em + i);
    const i32x4 b = *(const i32x4*)(eu + i);
    i32x4 rm, ru;
    rm.x = atomicAdd(&cnt[a.x], 1);
    rm.y = atomicAdd(&cnt[a.y], 1);
    rm.z = atomicAdd(&cnt[a.z], 1);
    rm.w = atomicAdd(&cnt[a.w], 1);
    ru.x = atomicAdd(&cnt[NM + b.x], 1);
    ru.y = atomicAdd(&cnt[NM + b.y], 1);
    ru.z = atomicAdd(&cnt[NM + b.z], 1);
    ru.w = atomicAdd(&cnt[NM + b.w], 1);
    *(i32x4*)(rank_m + i) = rm;
    *(i32x4*)(rank_u + i) = ru;
  }
}

// ---------------------------------------------------------------------------
// 3-phase parallel exclusive scan over cnt[NNODE] -> off.
// ---------------------------------------------------------------------------
__global__ __launch_bounds__(256) void scan_p1(const int* __restrict__ cnt,
                                               int* __restrict__ bsum) {
  const int b = blockIdx.x;
  const int t = threadIdx.x;
  const int idx = b * 1024 + t * 4;
  int s = 0;
  if (idx + 3 < NNODE) {
    const i32x4 v = *(const i32x4*)(cnt + idx);
    s = v.x + v.y + v.z + v.w;
  } else {
    for (int j = 0; j < 4; ++j) if (idx + j < NNODE) s += cnt[idx + j];
  }
  __shared__ int red[4];
  for (int d = 1; d < 64; d <<= 1) s += __shfl_xor(s, d);
  if ((t & 63) == 0) red[t >> 6] = s;
  __syncthreads();
  if (t == 0) bsum[b] = red[0] + red[1] + red[2] + red[3];
}

__global__ __launch_bounds__(1024) void scan_p2(const int* __restrict__ bsum,
                                                int* __restrict__ bpre) {
  __shared__ int sh[1024];
  const int t = threadIdx.x;
  const int v = (t < NCHUNK) ? bsum[t] : 0;
  sh[t] = v;
  __syncthreads();
  for (int d = 1; d < 1024; d <<= 1) {
    const int x = (t >= d) ? sh[t - d] : 0;
    __syncthreads();
    sh[t] += x;
    __syncthreads();
  }
  if (t < NCHUNK) bpre[t] = sh[t] - v;   // exclusive block prefix
}

__global__ __launch_bounds__(256) void scan_p3(const int* __restrict__ cnt,
                                               const int* __restrict__ bpre,
                                               int* __restrict__ off) {
  const int b = blockIdx.x;
  const int t = threadIdx.x;
  const int idx = b * 1024 + t * 4;
  i32x4 v = {0, 0, 0, 0};
  if (idx + 3 < NNODE) v = *(const i32x4*)(cnt + idx);
  else {
    if (idx     < NNODE) v.x = cnt[idx];
    if (idx + 1 < NNODE) v.y = cnt[idx + 1];
    if (idx + 2 < NNODE) v.z = cnt[idx + 2];
    if (idx + 3 < NNODE) v.w = cnt[idx + 3];
  }
  const int s = v.x + v.y + v.z + v.w;
  __shared__ int sh[256];
  sh[t] = s;
  __syncthreads();
  for (int d = 1; d < 256; d <<= 1) {
    const int x = (t >= d) ? sh[t - d] : 0;
    __syncthreads();
    sh[t] += x;
    __syncthreads();
  }
  const int pre = bpre[b] + sh[t] - s;
  i32x4 o;
  o.x = pre;
  o.y = pre + v.x;
  o.z = pre + v.x + v.y;
  o.w = pre + v.x + v.y + v.z;
  if (idx + 3 < NNODE) *(i32x4*)(off + idx) = o;
  else {
    if (idx     < NNODE) off[idx]     = o.x;
    if (idx + 1 < NNODE) off[idx + 1] = o.y;
    if (idx + 2 < NNODE) off[idx + 2] = o.z;
    if (idx + 3 < NNODE) off[idx + 3] = o.w;
  }
  if (b == 0 && t == 0) off[NNODE] = 2 * NE;
}

// ---------------------------------------------------------------------------
// Main fused MFMA kernel — flat schedule, single dispatch (R12 structure).
// rfeat loads are non-temporal (read-once input stream) so the randomly-
// gathered W tables keep Infinity-Cache residency.  All stores PLAIN (R14).
// NOTE: no min-waves clamp — VGPR ~108 is what this kernel needs (R9 lesson).
// ---------------------------------------------------------------------------
__global__ __launch_bounds__(256) void gcmc_main(
    const int* __restrict__ edges_u, const int* __restrict__ edges_m,
    const float* __restrict__ rfeat,
    const float* __restrict__ W_user, const float* __restrict__ W_movie,
    const float* __restrict__ ps_u, const float* __restrict__ rs_u, const float* __restrict__ rw_u,
    const float* __restrict__ ps_m, const float* __restrict__ rs_m, const float* __restrict__ rw_m,
    const float* __restrict__ user_cj, const float* __restrict__ movie_cj,
    const int* __restrict__ rank_m, const int* __restrict__ rank_u,
    const int* __restrict__ off,
    short* __restrict__ msg)
{
  const int r    = blockIdx.y;
  const int lane = threadIdx.x & 63;
  const int wid  = threadIdx.x >> 6;
  const int c    = lane & 15;
  const int kr   = lane >> 4;
  const int wtile = blockIdx.x * 4 + wid;
  if (wtile >= NTILE / 8) return;

  bf16x8 Bu[4][2], Bm[4][2], Bs[2];
#pragma unroll
  for (int t = 0; t < 4; ++t) {
#pragma unroll
    for (int s = 0; s < 2; ++s) {
      Bu[t][s] = cvt8(rw_u + ((size_t)r * DD + (4 * c + t)) * DD + s * 32 + kr * 8);
      Bm[t][s] = cvt8(rw_m + ((size_t)r * DD + (4 * c + t)) * DD + s * 32 + kr * 8);
    }
  }
#pragma unroll
  for (int s = 0; s < 2; ++s) {
    if (c < 4) {
      const float* v = (c == 0 ? rs_u : c == 1 ? ps_u : c == 2 ? rs_m : ps_m)
                       + r * DD + s * 32 + kr * 8;
      Bs[s] = cvt8(v);
    } else {
      bf16x8 z = {0, 0, 0, 0, 0, 0, 0, 0};
      Bs[s] = z;
    }
  }

#pragma unroll 1
  for (int tt = 0; tt < 8; ++tt) {
    const int tile = wtile * 8 + tt;
    const int e0 = tile * 16;

    // ---- A raw loads (read-once input stream -> non-temporal LOADS) ----
    const float* arow = rfeat + ((size_t)r * EE + e0 + c) * DD + kr * 8;
    const f32x4 fa0 = ntl_f4(arow);
    const f32x4 fa1 = ntl_f4(arow + 4);
    const f32x4 fa2 = ntl_f4(arow + 32);
    const f32x4 fa3 = ntl_f4(arow + 36);

    // ---- edge / rank loads (plain) ----
    const int ebase = r * EE + e0 + kr * 4;
    const i32x4 eu4  = *(const i32x4*)(edges_u + ebase);
    const i32x4 em4  = *(const i32x4*)(edges_m + ebase);
    const i32x4 rm4  = *(const i32x4*)(rank_m + ebase);
    const i32x4 ru4  = *(const i32x4*)(rank_u + ebase);
    const int eus[4] = {eu4.x, eu4.y, eu4.z, eu4.w};
    const int ems[4] = {em4.x, em4.y, em4.z, em4.w};
    const int rms[4] = {rm4.x, rm4.y, rm4.z, rm4.w};
    const int rus[4] = {ru4.x, ru4.y, ru4.z, ru4.w};

    // ---- dependent gathers (reused tables -> temporal), issued up-front ----
    int slm[4], slu[4];
    float cju[4], cjm[4];
    f32x4 hu[4], hm[4];
#pragma unroll
    for (int q = 0; q < 4; ++q) {
      slm[q] = off[ems[q]] + rms[q];
      slu[q] = off[NM + eus[q]] + rus[q];
      cju[q] = user_cj[eus[q]];
      cjm[q] = movie_cj[ems[q]];
      hu[q]  = *(const f32x4*)(W_user  + ((size_t)r * NU + eus[q]) * DD + 4 * c);
      hm[q]  = *(const f32x4*)(W_movie + ((size_t)r * NM + ems[q]) * DD + 4 * c);
    }

    const bf16x8 A0 = pack8e(fa0, fa1);
    const bf16x8 A1 = pack8e(fa2, fa3);
    f32x4 z4 = {0.f, 0.f, 0.f, 0.f};
    f32x4 Cu[4], Cm[4], Cs;
#pragma unroll
    for (int t = 0; t < 4; ++t) { Cu[t] = z4; Cm[t] = z4; }
    Cs = z4;
#pragma unroll
    for (int t = 0; t < 4; ++t) {
      Cu[t] = __builtin_amdgcn_mfma_f32_16x16x32_bf16(A0, Bu[t][0], Cu[t], 0, 0, 0);
      Cu[t] = __builtin_amdgcn_mfma_f32_16x16x32_bf16(A1, Bu[t][1], Cu[t], 0, 0, 0);
      Cm[t] = __builtin_amdgcn_mfma_f32_16x16x32_bf16(A0, Bm[t][0], Cm[t], 0, 0, 0);
      Cm[t] = __builtin_amdgcn_mfma_f32_16x16x32_bf16(A1, Bm[t][1], Cm[t], 0, 0, 0);
    }
    Cs = __builtin_amdgcn_mfma_f32_16x16x32_bf16(A0, Bs[0], Cs, 0, 0, 0);
    Cs = __builtin_amdgcn_mfma_f32_16x16x32_bf16(A1, Bs[1], Cs, 0, 0, 0);

#pragma unroll
    for (int q = 0; q < 4; ++q) {
      const int src = (lane & 48);
      const float su = __shfl(Cs[q], src);
      const float pu = __shfl(Cs[q], src | 1);
      const float sm = __shfl(Cs[q], src | 2);
      const float pm = __shfl(Cs[q], src | 3);
      const float sgu = sigm(su), pau = sigm(pu);
      const float sgm_ = sigm(sm), pam = sigm(pm);

      short4 vm, vu;
      vm.x = f2bf((hu[q].x * pau + Cu[0][q] * sgu) * cju[q]);
      vm.y = f2bf((hu[q].y * pau + Cu[1][q] * sgu) * cju[q]);
      vm.z = f2bf((hu[q].z * pau + Cu[2][q] * sgu) * cju[q]);
      vm.w = f2bf((hu[q].w * pau + Cu[3][q] * sgu) * cju[q]);
      vu.x = f2bf((hm[q].x * pam + Cm[0][q] * sgm_) * cjm[q]);
      vu.y = f2bf((hm[q].y * pam + Cm[1][q] * sgm_) * cjm[q]);
      vu.z = f2bf((hm[q].z * pam + Cm[2][q] * sgm_) * cjm[q]);
      vu.w = f2bf((hm[q].w * pam + Cm[3][q] * sgm_) * cjm[q]);

      *(short4*)(msg + ((size_t)slm[q] << 6) + 4 * c) = vm;   // plain stores
      *(short4*)(msg + ((size_t)slu[q] << 6) + 4 * c) = vu;
    }
  }
}

// ---------------------------------------------------------------------------
// Merged gather-reduce (one dispatch), plain loads throughout.
//  blocks [0, GM_BLOCKS): movies — one wave per movie, 8 rows/instr, 4-deep.
//  blocks [GM_BLOCKS, +GU_BLOCKS): users — 8 lanes/user, 32 users/block, 4-deep.
// ---------------------------------------------------------------------------
__global__ __launch_bounds__(256) void gather_k(const int* __restrict__ off,
                                                const short* __restrict__ msg,
                                                float* __restrict__ out)
{
  if (blockIdx.x < GM_BLOCKS) {
    const int w    = blockIdx.x * 4 + (threadIdx.x >> 6);   // movie id
    const int lane = threadIdx.x & 63;
    const int sub  = lane >> 3;    // row group 0..7
    const int c8   = lane & 7;     // 16-byte chunk

    const int s0 = off[w];
    const int e1 = off[w + 1];

    float a0[8] = {0,0,0,0,0,0,0,0};
    float a1[8] = {0,0,0,0,0,0,0,0};
    float a2[8] = {0,0,0,0,0,0,0,0};
    float a3[8] = {0,0,0,0,0,0,0,0};
    int k = s0 + sub;
    for (; k + 24 < e1; k += 32) {
      const s16x8 v0 = *(const s16x8*)(msg + ((size_t)k << 6) + 8 * c8);
      const s16x8 v1 = *(const s16x8*)(msg + ((size_t)(k + 8) << 6) + 8 * c8);
      const s16x8 v2 = *(const s16x8*)(msg + ((size_t)(k + 16) << 6) + 8 * c8);
      const s16x8 v3 = *(const s16x8*)(msg + ((size_t)(k + 24) << 6) + 8 * c8);
#pragma unroll
      for (int j = 0; j < 8; ++j) {
        a0[j] += bf2f(v0[j]); a1[j] += bf2f(v1[j]);
        a2[j] += bf2f(v2[j]); a3[j] += bf2f(v3[j]);
      }
    }
    for (; k < e1; k += 8) {
      const s16x8 v0 = *(const s16x8*)(msg + ((size_t)k << 6) + 8 * c8);
#pragma unroll
      for (int j = 0; j < 8; ++j) a0[j] += bf2f(v0[j]);
    }
#pragma unroll
    for (int j = 0; j < 8; ++j) {
      a0[j] += a1[j] + a2[j] + a3[j];
      a0[j] += __shfl_xor(a0[j], 8);
      a0[j] += __shfl_xor(a0[j], 16);
      a0[j] += __shfl_xor(a0[j], 32);
    }
    if (sub == 0) {
      float* dst = out + (size_t)NU * DD + (size_t)w * DD + 8 * c8;
      f32x4 o0 = {a0[0], a0[1], a0[2], a0[3]};
      f32x4 o1 = {a0[4], a0[5], a0[6], a0[7]};
      *(f32x4*)dst = o0;
      *(f32x4*)(dst + 4) = o1;
    }
  } else {
    const int u  = (blockIdx.x - GM_BLOCKS) * 32 + (threadIdx.x >> 3);   // user id
    const int c8 = threadIdx.x & 7;

    const int s0 = off[NM + u];
    const int e1 = off[NM + u + 1];

    float a0[8] = {0,0,0,0,0,0,0,0};
    float a1[8] = {0,0,0,0,0,0,0,0};
    float a2[8] = {0,0,0,0,0,0,0,0};
    float a3[8] = {0,0,0,0,0,0,0,0};
    int k = s0;
    for (; k + 3 < e1; k += 4) {
      const s16x8 v0 = *(const s16x8*)(msg + ((size_t)k << 6) + 8 * c8);
      const s16x8 v1 = *(const s16x8*)(msg + ((size_t)(k + 1) << 6) + 8 * c8);
      const s16x8 v2 = *(const s16x8*)(msg + ((size_t)(k + 2) << 6) + 8 * c8);
      const s16x8 v3 = *(const s16x8*)(msg + ((size_t)(k + 3) << 6) + 8 * c8);
#pragma unroll
      for (int j = 0; j < 8; ++j) {
        a0[j] += bf2f(v0[j]); a1[j] += bf2f(v1[j]);
        a2[j] += bf2f(v2[j]); a3[j] += bf2f(v3[j]);
      }
    }
    for (; k < e1; ++k) {
      const s16x8 v0 = *(const s16x8*)(msg + ((size_t)k << 6) + 8 * c8);
#pragma unroll
      for (int j = 0; j < 8; ++j) a0[j] += bf2f(v0[j]);
    }
    float* dst = out + (size_t)u * DD + 8 * c8;
    f32x4 o0, o1;
    o0.x = a0[0] + a1[0] + a2[0] + a3[0];
    o0.y = a0[1] + a1[1] + a2[1] + a3[1];
    o0.z = a0[2] + a1[2] + a2[2] + a3[2];
    o0.w = a0[3] + a1[3] + a2[3] + a3[3];
    o1.x = a0[4] + a1[4] + a2[4] + a3[4];
    o1.y = a0[5] + a1[5] + a2[5] + a3[5];
    o1.z = a0[6] + a1[6] + a2[6] + a3[6];
    o1.w = a0[7] + a1[7] + a2[7] + a3[7];
    *(f32x4*)dst = o0;
    *(f32x4*)(dst + 4) = o1;
  }
}

// ---------------------------------------------------------------------------
// FC kernel (in-place on d_out): row -> gelu(row*ci) @ W.T + b, 16 rows/wave.
// ---------------------------------------------------------------------------
__global__ __launch_bounds__(256) void gcmc_fc(
    float* __restrict__ out,
    const float* __restrict__ user_ci, const float* __restrict__ movie_ci,
    const float* __restrict__ ufc_w, const float* __restrict__ ufc_b,
    const float* __restrict__ ifc_w, const float* __restrict__ ifc_b)
{
  const int wt   = blockIdx.x * 4 + (threadIdx.x >> 6);
  const int lane = threadIdx.x & 63;
  const int c    = lane & 15;
  const int kr   = lane >> 4;
  const bool isU = wt < (NU / 16);
  float* base        = isU ? out : out + (size_t)NU * DD;
  const float* ci    = isU ? user_ci : movie_ci;
  const float* W     = isU ? ufc_w : ifc_w;
  const float* bias  = isU ? ufc_b : ifc_b;
  const int row0 = (isU ? wt : wt - (NU / 16)) * 16;

  bf16x8 B[4][2];
#pragma unroll
  for (int t = 0; t < 4; ++t)
#pragma unroll
    for (int s = 0; s < 2; ++s)
      B[t][s] = cvt8(W + (size_t)(4 * c + t) * DD + s * 32 + kr * 8);

  const float civ = ci[row0 + c];
  const float* arow = base + (size_t)(row0 + c) * DD + kr * 8;

  bf16x8 A0, A1;
  {
    const f32x4 a = *(const f32x4*)arow;
    const f32x4 b = *(const f32x4*)(arow + 4);
    const f32x4 a2 = *(const f32x4*)(arow + 32);
    const f32x4 b2 = *(const f32x4*)(arow + 36);
    A0[0] = f2bf(gelu(a.x * civ));  A0[1] = f2bf(gelu(a.y * civ));
    A0[2] = f2bf(gelu(a.z * civ));  A0[3] = f2bf(gelu(a.w * civ));
    A0[4] = f2bf(gelu(b.x * civ));  A0[5] = f2bf(gelu(b.y * civ));
    A0[6] = f2bf(gelu(b.z * civ));  A0[7] = f2bf(gelu(b.w * civ));
    A1[0] = f2bf(gelu(a2.x * civ)); A1[1] = f2bf(gelu(a2.y * civ));
    A1[2] = f2bf(gelu(a2.z * civ)); A1[3] = f2bf(gelu(a2.w * civ));
    A1[4] = f2bf(gelu(b2.x * civ)); A1[5] = f2bf(gelu(b2.y * civ));
    A1[6] = f2bf(gelu(b2.z * civ)); A1[7] = f2bf(gelu(b2.w * civ));
  }

  f32x4 z4 = {0.f, 0.f, 0.f, 0.f};
  f32x4 C[4];
#pragma unroll
  for (int t = 0; t < 4; ++t) {
    C[t] = z4;
    C[t] = __builtin_amdgcn_mfma_f32_16x16x32_bf16(A0, B[t][0], C[t], 0, 0, 0);
    C[t] = __builtin_amdgcn_mfma_f32_16x16x32_bf16(A1, B[t][1], C[t], 0, 0, 0);
  }

  const f32x4 b4 = *(const f32x4*)(bias + 4 * c);
#pragma unroll
  for (int q = 0; q < 4; ++q) {
    const int row = row0 + kr * 4 + q;
    f32x4 o;
    o.x = C[0][q] + b4.x; o.y = C[1][q] + b4.y;
    o.z = C[2][q] + b4.z; o.w = C[3][q] + b4.w;
    *(f32x4*)(base + (size_t)row * DD + 4 * c) = o;
  }
}

extern "C" void kernel_launch(void* const* d_in, const int* in_sizes, int n_in,
                              void* d_out, int out_size, void* d_ws, size_t ws_size,
                              hipStream_t stream) {
  const int*   edges_u  = (const int*)  d_in[0];
  const int*   edges_m  = (const int*)  d_in[1];
  const float* rfeat    = (const float*)d_in[2];
  const float* W_user   = (const float*)d_in[3];
  const float* W_movie  = (const float*)d_in[4];
  const float* ps_u     = (const float*)d_in[5];
  const float* rs_u     = (const float*)d_in[6];
  const float* rw_u     = (const float*)d_in[7];
  const float* ps_m     = (const float*)d_in[8];
  const float* rs_m     = (const float*)d_in[9];
  const float* rw_m     = (const float*)d_in[10];
  const float* user_cj  = (const float*)d_in[11];
  const float* user_ci  = (const float*)d_in[12];
  const float* movie_cj = (const float*)d_in[13];
  const float* movie_ci = (const float*)d_in[14];
  const float* ufc_w    = (const float*)d_in[15];
  const float* ufc_b    = (const float*)d_in[16];
  const float* ifc_w    = (const float*)d_in[17];
  const float* ifc_b    = (const float*)d_in[18];

  float* out = (float*)d_out;

  // ---- workspace layout ----
  char* ws = (char*)d_ws;
  size_t o = 0;
  auto alloc = [&](size_t bytes) { char* p = ws + o; o += (bytes + 255) & ~(size_t)255; return p; };
  int*   cnt    = (int*)  alloc(sizeof(int) * NNODE);
  int*   off    = (int*)  alloc(sizeof(int) * (NNODE + 1));
  int*   bsum   = (int*)  alloc(sizeof(int) * NCHUNK);
  int*   bpre   = (int*)  alloc(sizeof(int) * NCHUNK);
  int*   rank_m = (int*)  alloc(sizeof(int) * NE);
  int*   rank_u = (int*)  alloc(sizeof(int) * NE);
  short* msg    = (short*)alloc(sizeof(short) * (size_t)2 * NE * DD);   // 512 MB
  (void)ws_size;

  hipMemsetAsync(cnt, 0, sizeof(int) * NNODE, stream);
  rank0_k<<<(NE / 4 + 255) / 256, 256, 0, stream>>>(edges_u, edges_m, cnt, rank_m, rank_u);
  scan_p1<<<NCHUNK, 256, 0, stream>>>(cnt, bsum);
  scan_p2<<<1, 1024, 0, stream>>>(bsum, bpre);
  scan_p3<<<NCHUNK, 256, 0, stream>>>(cnt, bpre, off);

  dim3 g1((NTILE / 8 + 3) / 4, RR);   // (782, 5)
  gcmc_main<<<g1, 256, 0, stream>>>(edges_u, edges_m, rfeat, W_user, W_movie,
                                    ps_u, rs_u, rw_u, ps_m, rs_m, rw_m,
                                    user_cj, movie_cj, rank_m, rank_u, off, msg);

  gather_k<<<GM_BLOCKS + GU_BLOCKS, 256, 0, stream>>>(off, msg, out);

  gcmc_fc<<<(NNODE / 16) / 4, 256, 0, stream>>>(out, user_ci, movie_ci,
                                                ufc_w, ufc_b, ifc_w, ifc_b);
}

// Round 16
// 711.708 us; speedup vs baseline: 1.0018x; 1.0018x over previous
//
#include <hip/hip_runtime.h>
#include <hip/hip_bf16.h>

#define NU 100000
#define NM 20000
#define DD 64
#define RR 5
#define EE 400000
#define NE (RR * EE)            // 2,000,000 edges per direction
#define NNODE (NM + NU)         // 120,000 destination bins (movies first)
#define NTILE (EE / 16)         // 25,000 16-edge tiles per relation
#define NCHUNK ((NNODE + 1023) / 1024)   // 118 scan chunks
#define GM_BLOCKS (NM / 4)      // 5000 movie-gather blocks (4 movies/block)
#define GU_BLOCKS (NU / 32)     // 3125 user-gather blocks (32 users/block)

typedef __attribute__((ext_vector_type(8))) short bf16x8;
typedef __attribute__((ext_vector_type(8))) short s16x8;
typedef __attribute__((ext_vector_type(4))) int   i32x4;
typedef __attribute__((ext_vector_type(4))) float f32x4;

static __device__ __forceinline__ short f2bf(float f) {
  return __builtin_bit_cast(short, __float2bfloat16(f));
}
static __device__ __forceinline__ float bf2f(short s) {
  return __builtin_bit_cast(float, ((unsigned)(unsigned short)s) << 16);
}

// nt LOAD of host-written, read-once input only (rfeat). R14 lesson: nt
// STORES consumed by a later kernel corrupt data on gfx950 — never again.
static __device__ __forceinline__ f32x4 ntl_f4(const float* __restrict__ p) {
  return __builtin_nontemporal_load((const f32x4*)p);
}

static __device__ __forceinline__ bf16x8 pack8e(const f32x4 a, const f32x4 b) {
  bf16x8 o;
  o[0] = f2bf(a.x); o[1] = f2bf(a.y); o[2] = f2bf(a.z); o[3] = f2bf(a.w);
  o[4] = f2bf(b.x); o[5] = f2bf(b.y); o[6] = f2bf(b.z); o[7] = f2bf(b.w);
  return o;
}
static __device__ __forceinline__ bf16x8 cvt8(const float* __restrict__ p) {
  return pack8e(*(const f32x4*)p, *(const f32x4*)(p + 4));
}

static __device__ __forceinline__ float sigm(float x) { return 1.f / (1.f + __expf(-x)); }
static __device__ __forceinline__ float gelu(float x) {
  return 0.5f * x * (1.f + erff(x * 0.70710678118654752f));
}

// ---------------------------------------------------------------------------
// rank0: ONE atomic pass. cnt (zeroed) -> per-edge rank within destination,
// and cnt ends up holding the per-node degree.
// ---------------------------------------------------------------------------
__global__ __launch_bounds__(256) void rank0_k(const int* __restrict__ eu,
                                               const int* __restrict__ em,
                                               int* __restrict__ cnt,
                                               int* __restrict__ rank_m,
                                               int* __restrict__ rank_u) {
  const int i = (blockIdx.x * 256 + threadIdx.x) * 4;
  if (i < NE) {
    const i32x4 a = *(const i32x4*)(em + i);
    const i32x4 b = *(const i32x4*)(eu + i);
    i32x4 rm, ru;
    rm.x = atomicAdd(&cnt[a.x], 1);
    rm.y = atomicAdd(&cnt[a.y], 1);
    rm.z = atomicAdd(&cnt[a.z], 1);
    rm.w = atomicAdd(&cnt[a.w], 1);
    ru.x = atomicAdd(&cnt[NM + b.x], 1);
    ru.y = atomicAdd(&cnt[NM + b.y], 1);
    ru.z = atomicAdd(&cnt[NM + b.z], 1);
    ru.w = atomicAdd(&cnt[NM + b.w], 1);
    *(i32x4*)(rank_m + i) = rm;
    *(i32x4*)(rank_u + i) = ru;
  }
}

// ---------------------------------------------------------------------------
// ONE-dispatch scan (replaces 3-phase): off need not be globally ordered,
// only disjoint with per-node contiguity — main uses off[dst]+rank, gather
// uses len=cnt[w]. Each block reserves its range via one atomicAdd on a
// global cursor, then writes its local exclusive scan.
// ---------------------------------------------------------------------------
__global__ __launch_bounds__(256) void scan_k(const int* __restrict__ cnt,
                                              int* __restrict__ cursor,
                                              int* __restrict__ off) {
  const int b = blockIdx.x;
  const int t = threadIdx.x;
  const int idx = b * 1024 + t * 4;
  i32x4 v = {0, 0, 0, 0};
  if (idx + 3 < NNODE) v = *(const i32x4*)(cnt + idx);
  else {
    if (idx     < NNODE) v.x = cnt[idx];
    if (idx + 1 < NNODE) v.y = cnt[idx + 1];
    if (idx + 2 < NNODE) v.z = cnt[idx + 2];
    if (idx + 3 < NNODE) v.w = cnt[idx + 3];
  }
  const int s = v.x + v.y + v.z + v.w;
  __shared__ int sh[256];
  __shared__ int base_sh;
  sh[t] = s;
  __syncthreads();
  for (int d = 1; d < 256; d <<= 1) {
    const int x = (t >= d) ? sh[t - d] : 0;
    __syncthreads();
    sh[t] += x;
    __syncthreads();
  }
  if (t == 255) base_sh = atomicAdd(cursor, sh[255]);   // reserve block range
  __syncthreads();
  const int pre = base_sh + sh[t] - s;
  i32x4 o;
  o.x = pre;
  o.y = pre + v.x;
  o.z = pre + v.x + v.y;
  o.w = pre + v.x + v.y + v.z;
  if (idx + 3 < NNODE) *(i32x4*)(off + idx) = o;
  else {
    if (idx     < NNODE) off[idx]     = o.x;
    if (idx + 1 < NNODE) off[idx + 1] = o.y;
    if (idx + 2 < NNODE) off[idx + 2] = o.z;
    if (idx + 3 < NNODE) off[idx + 3] = o.w;
  }
}

// ---------------------------------------------------------------------------
// Main fused MFMA kernel — flat schedule, single dispatch (best measured).
// rfeat loads non-temporal (read-once stream; keeps W tables L3-resident).
// All stores plain (R14).  No min-waves clamp (R9: VGPR clamp -> spills).
// ---------------------------------------------------------------------------
__global__ __launch_bounds__(256) void gcmc_main(
    const int* __restrict__ edges_u, const int* __restrict__ edges_m,
    const float* __restrict__ rfeat,
    const float* __restrict__ W_user, const float* __restrict__ W_movie,
    const float* __restrict__ ps_u, const float* __restrict__ rs_u, const float* __restrict__ rw_u,
    const float* __restrict__ ps_m, const float* __restrict__ rs_m, const float* __restrict__ rw_m,
    const float* __restrict__ user_cj, const float* __restrict__ movie_cj,
    const int* __restrict__ rank_m, const int* __restrict__ rank_u,
    const int* __restrict__ off,
    short* __restrict__ msg)
{
  const int r    = blockIdx.y;
  const int lane = threadIdx.x & 63;
  const int wid  = threadIdx.x >> 6;
  const int c    = lane & 15;
  const int kr   = lane >> 4;
  const int wtile = blockIdx.x * 4 + wid;
  if (wtile >= NTILE / 8) return;

  bf16x8 Bu[4][2], Bm[4][2], Bs[2];
#pragma unroll
  for (int t = 0; t < 4; ++t) {
#pragma unroll
    for (int s = 0; s < 2; ++s) {
      Bu[t][s] = cvt8(rw_u + ((size_t)r * DD + (4 * c + t)) * DD + s * 32 + kr * 8);
      Bm[t][s] = cvt8(rw_m + ((size_t)r * DD + (4 * c + t)) * DD + s * 32 + kr * 8);
    }
  }
#pragma unroll
  for (int s = 0; s < 2; ++s) {
    if (c < 4) {
      const float* v = (c == 0 ? rs_u : c == 1 ? ps_u : c == 2 ? rs_m : ps_m)
                       + r * DD + s * 32 + kr * 8;
      Bs[s] = cvt8(v);
    } else {
      bf16x8 z = {0, 0, 0, 0, 0, 0, 0, 0};
      Bs[s] = z;
    }
  }

#pragma unroll 1
  for (int tt = 0; tt < 8; ++tt) {
    const int tile = wtile * 8 + tt;
    const int e0 = tile * 16;

    const float* arow = rfeat + ((size_t)r * EE + e0 + c) * DD + kr * 8;
    const f32x4 fa0 = ntl_f4(arow);
    const f32x4 fa1 = ntl_f4(arow + 4);
    const f32x4 fa2 = ntl_f4(arow + 32);
    const f32x4 fa3 = ntl_f4(arow + 36);

    const int ebase = r * EE + e0 + kr * 4;
    const i32x4 eu4  = *(const i32x4*)(edges_u + ebase);
    const i32x4 em4  = *(const i32x4*)(edges_m + ebase);
    const i32x4 rm4  = *(const i32x4*)(rank_m + ebase);
    const i32x4 ru4  = *(const i32x4*)(rank_u + ebase);
    const int eus[4] = {eu4.x, eu4.y, eu4.z, eu4.w};
    const int ems[4] = {em4.x, em4.y, em4.z, em4.w};
    const int rms[4] = {rm4.x, rm4.y, rm4.z, rm4.w};
    const int rus[4] = {ru4.x, ru4.y, ru4.z, ru4.w};

    int slm[4], slu[4];
    float cju[4], cjm[4];
    f32x4 hu[4], hm[4];
#pragma unroll
    for (int q = 0; q < 4; ++q) {
      slm[q] = off[ems[q]] + rms[q];
      slu[q] = off[NM + eus[q]] + rus[q];
      cju[q] = user_cj[eus[q]];
      cjm[q] = movie_cj[ems[q]];
      hu[q]  = *(const f32x4*)(W_user  + ((size_t)r * NU + eus[q]) * DD + 4 * c);
      hm[q]  = *(const f32x4*)(W_movie + ((size_t)r * NM + ems[q]) * DD + 4 * c);
    }

    const bf16x8 A0 = pack8e(fa0, fa1);
    const bf16x8 A1 = pack8e(fa2, fa3);
    f32x4 z4 = {0.f, 0.f, 0.f, 0.f};
    f32x4 Cu[4], Cm[4], Cs;
#pragma unroll
    for (int t = 0; t < 4; ++t) { Cu[t] = z4; Cm[t] = z4; }
    Cs = z4;
#pragma unroll
    for (int t = 0; t < 4; ++t) {
      Cu[t] = __builtin_amdgcn_mfma_f32_16x16x32_bf16(A0, Bu[t][0], Cu[t], 0, 0, 0);
      Cu[t] = __builtin_amdgcn_mfma_f32_16x16x32_bf16(A1, Bu[t][1], Cu[t], 0, 0, 0);
      Cm[t] = __builtin_amdgcn_mfma_f32_16x16x32_bf16(A0, Bm[t][0], Cm[t], 0, 0, 0);
      Cm[t] = __builtin_amdgcn_mfma_f32_16x16x32_bf16(A1, Bm[t][1], Cm[t], 0, 0, 0);
    }
    Cs = __builtin_amdgcn_mfma_f32_16x16x32_bf16(A0, Bs[0], Cs, 0, 0, 0);
    Cs = __builtin_amdgcn_mfma_f32_16x16x32_bf16(A1, Bs[1], Cs, 0, 0, 0);

#pragma unroll
    for (int q = 0; q < 4; ++q) {
      const int src = (lane & 48);
      const float su = __shfl(Cs[q], src);
      const float pu = __shfl(Cs[q], src | 1);
      const float sm = __shfl(Cs[q], src | 2);
      const float pm = __shfl(Cs[q], src | 3);
      const float sgu = sigm(su), pau = sigm(pu);
      const float sgm_ = sigm(sm), pam = sigm(pm);

      short4 vm, vu;
      vm.x = f2bf((hu[q].x * pau + Cu[0][q] * sgu) * cju[q]);
      vm.y = f2bf((hu[q].y * pau + Cu[1][q] * sgu) * cju[q]);
      vm.z = f2bf((hu[q].z * pau + Cu[2][q] * sgu) * cju[q]);
      vm.w = f2bf((hu[q].w * pau + Cu[3][q] * sgu) * cju[q]);
      vu.x = f2bf((hm[q].x * pam + Cm[0][q] * sgm_) * cjm[q]);
      vu.y = f2bf((hm[q].y * pam + Cm[1][q] * sgm_) * cjm[q]);
      vu.z = f2bf((hm[q].z * pam + Cm[2][q] * sgm_) * cjm[q]);
      vu.w = f2bf((hm[q].w * pam + Cm[3][q] * sgm_) * cjm[q]);

      *(short4*)(msg + ((size_t)slm[q] << 6) + 4 * c) = vm;
      *(short4*)(msg + ((size_t)slu[q] << 6) + 4 * c) = vu;
    }
  }
}

// ---------------------------------------------------------------------------
// Merged gather-reduce (one dispatch).  Segment = [off[w], off[w]+cnt[w]).
//  blocks [0, GM_BLOCKS): movies — one wave per movie, 8 rows/instr, 4-deep.
//  blocks [GM_BLOCKS, +GU_BLOCKS): users — 8 lanes/user, 32 users/block, 4-deep.
// ---------------------------------------------------------------------------
__global__ __launch_bounds__(256) void gather_k(const int* __restrict__ off,
                                                const int* __restrict__ cnt,
                                                const short* __restrict__ msg,
                                                float* __restrict__ out)
{
  if (blockIdx.x < GM_BLOCKS) {
    const int w    = blockIdx.x * 4 + (threadIdx.x >> 6);   // movie id
    const int lane = threadIdx.x & 63;
    const int sub  = lane >> 3;    // row group 0..7
    const int c8   = lane & 7;     // 16-byte chunk

    const int s0 = off[w];
    const int e1 = s0 + cnt[w];

    float a0[8] = {0,0,0,0,0,0,0,0};
    float a1[8] = {0,0,0,0,0,0,0,0};
    float a2[8] = {0,0,0,0,0,0,0,0};
    float a3[8] = {0,0,0,0,0,0,0,0};
    int k = s0 + sub;
    for (; k + 24 < e1; k += 32) {
      const s16x8 v0 = *(const s16x8*)(msg + ((size_t)k << 6) + 8 * c8);
      const s16x8 v1 = *(const s16x8*)(msg + ((size_t)(k + 8) << 6) + 8 * c8);
      const s16x8 v2 = *(const s16x8*)(msg + ((size_t)(k + 16) << 6) + 8 * c8);
      const s16x8 v3 = *(const s16x8*)(msg + ((size_t)(k + 24) << 6) + 8 * c8);
#pragma unroll
      for (int j = 0; j < 8; ++j) {
        a0[j] += bf2f(v0[j]); a1[j] += bf2f(v1[j]);
        a2[j] += bf2f(v2[j]); a3[j] += bf2f(v3[j]);
      }
    }
    for (; k < e1; k += 8) {
      const s16x8 v0 = *(const s16x8*)(msg + ((size_t)k << 6) + 8 * c8);
#pragma unroll
      for (int j = 0; j < 8; ++j) a0[j] += bf2f(v0[j]);
    }
#pragma unroll
    for (int j = 0; j < 8; ++j) {
      a0[j] += a1[j] + a2[j] + a3[j];
      a0[j] += __shfl_xor(a0[j], 8);
      a0[j] += __shfl_xor(a0[j], 16);
      a0[j] += __shfl_xor(a0[j], 32);
    }
    if (sub == 0) {
      float* dst = out + (size_t)NU * DD + (size_t)w * DD + 8 * c8;
      f32x4 o0 = {a0[0], a0[1], a0[2], a0[3]};
      f32x4 o1 = {a0[4], a0[5], a0[6], a0[7]};
      *(f32x4*)dst = o0;
      *(f32x4*)(dst + 4) = o1;
    }
  } else {
    const int u  = (blockIdx.x - GM_BLOCKS) * 32 + (threadIdx.x >> 3);   // user id
    const int c8 = threadIdx.x & 7;

    const int s0 = off[NM + u];
    const int e1 = s0 + cnt[NM + u];

    float a0[8] = {0,0,0,0,0,0,0,0};
    float a1[8] = {0,0,0,0,0,0,0,0};
    float a2[8] = {0,0,0,0,0,0,0,0};
    float a3[8] = {0,0,0,0,0,0,0,0};
    int k = s0;
    for (; k + 3 < e1; k += 4) {
      const s16x8 v0 = *(const s16x8*)(msg + ((size_t)k << 6) + 8 * c8);
      const s16x8 v1 = *(const s16x8*)(msg + ((size_t)(k + 1) << 6) + 8 * c8);
      const s16x8 v2 = *(const s16x8*)(msg + ((size_t)(k + 2) << 6) + 8 * c8);
      const s16x8 v3 = *(const s16x8*)(msg + ((size_t)(k + 3) << 6) + 8 * c8);
#pragma unroll
      for (int j = 0; j < 8; ++j) {
        a0[j] += bf2f(v0[j]); a1[j] += bf2f(v1[j]);
        a2[j] += bf2f(v2[j]); a3[j] += bf2f(v3[j]);
      }
    }
    for (; k < e1; ++k) {
      const s16x8 v0 = *(const s16x8*)(msg + ((size_t)k << 6) + 8 * c8);
#pragma unroll
      for (int j = 0; j < 8; ++j) a0[j] += bf2f(v0[j]);
    }
    float* dst = out + (size_t)u * DD + 8 * c8;
    f32x4 o0, o1;
    o0.x = a0[0] + a1[0] + a2[0] + a3[0];
    o0.y = a0[1] + a1[1] + a2[1] + a3[1];
    o0.z = a0[2] + a1[2] + a2[2] + a3[2];
    o0.w = a0[3] + a1[3] + a2[3] + a3[3];
    o1.x = a0[4] + a1[4] + a2[4] + a3[4];
    o1.y = a0[5] + a1[5] + a2[5] + a3[5];
    o1.z = a0[6] + a1[6] + a2[6] + a3[6];
    o1.w = a0[7] + a1[7] + a2[7] + a3[7];
    *(f32x4*)dst = o0;
    *(f32x4*)(dst + 4) = o1;
  }
}

// ---------------------------------------------------------------------------
// FC kernel (in-place on d_out): row -> gelu(row*ci) @ W.T + b, 16 rows/wave.
// ---------------------------------------------------------------------------
__global__ __launch_bounds__(256) void gcmc_fc(
    float* __restrict__ out,
    const float* __restrict__ user_ci, const float* __restrict__ movie_ci,
    const float* __restrict__ ufc_w, const float* __restrict__ ufc_b,
    const float* __restrict__ ifc_w, const float* __restrict__ ifc_b)
{
  const int wt   = blockIdx.x * 4 + (threadIdx.x >> 6);
  const int lane = threadIdx.x & 63;
  const int c    = lane & 15;
  const int kr   = lane >> 4;
  const bool isU = wt < (NU / 16);
  float* base        = isU ? out : out + (size_t)NU * DD;
  const float* ci    = isU ? user_ci : movie_ci;
  const float* W     = isU ? ufc_w : ifc_w;
  const float* bias  = isU ? ufc_b : ifc_b;
  const int row0 = (isU ? wt : wt - (NU / 16)) * 16;

  bf16x8 B[4][2];
#pragma unroll
  for (int t = 0; t < 4; ++t)
#pragma unroll
    for (int s = 0; s < 2; ++s)
      B[t][s] = cvt8(W + (size_t)(4 * c + t) * DD + s * 32 + kr * 8);

  const float civ = ci[row0 + c];
  const float* arow = base + (size_t)(row0 + c) * DD + kr * 8;

  bf16x8 A0, A1;
  {
    const f32x4 a = *(const f32x4*)arow;
    const f32x4 b = *(const f32x4*)(arow + 4);
    const f32x4 a2 = *(const f32x4*)(arow + 32);
    const f32x4 b2 = *(const f32x4*)(arow + 36);
    A0[0] = f2bf(gelu(a.x * civ));  A0[1] = f2bf(gelu(a.y * civ));
    A0[2] = f2bf(gelu(a.z * civ));  A0[3] = f2bf(gelu(a.w * civ));
    A0[4] = f2bf(gelu(b.x * civ));  A0[5] = f2bf(gelu(b.y * civ));
    A0[6] = f2bf(gelu(b.z * civ));  A0[7] = f2bf(gelu(b.w * civ));
    A1[0] = f2bf(gelu(a2.x * civ)); A1[1] = f2bf(gelu(a2.y * civ));
    A1[2] = f2bf(gelu(a2.z * civ)); A1[3] = f2bf(gelu(a2.w * civ));
    A1[4] = f2bf(gelu(b2.x * civ)); A1[5] = f2bf(gelu(b2.y * civ));
    A1[6] = f2bf(gelu(b2.z * civ)); A1[7] = f2bf(gelu(b2.w * civ));
  }

  f32x4 z4 = {0.f, 0.f, 0.f, 0.f};
  f32x4 C[4];
#pragma unroll
  for (int t = 0; t < 4; ++t) {
    C[t] = z4;
    C[t] = __builtin_amdgcn_mfma_f32_16x16x32_bf16(A0, B[t][0], C[t], 0, 0, 0);
    C[t] = __builtin_amdgcn_mfma_f32_16x16x32_bf16(A1, B[t][1], C[t], 0, 0, 0);
  }

  const f32x4 b4 = *(const f32x4*)(bias + 4 * c);
#pragma unroll
  for (int q = 0; q < 4; ++q) {
    const int row = row0 + kr * 4 + q;
    f32x4 o;
    o.x = C[0][q] + b4.x; o.y = C[1][q] + b4.y;
    o.z = C[2][q] + b4.z; o.w = C[3][q] + b4.w;
    *(f32x4*)(base + (size_t)row * DD + 4 * c) = o;
  }
}

extern "C" void kernel_launch(void* const* d_in, const int* in_sizes, int n_in,
                              void* d_out, int out_size, void* d_ws, size_t ws_size,
                              hipStream_t stream) {
  const int*   edges_u  = (const int*)  d_in[0];
  const int*   edges_m  = (const int*)  d_in[1];
  const float* rfeat    = (const float*)d_in[2];
  const float* W_user   = (const float*)d_in[3];
  const float* W_movie  = (const float*)d_in[4];
  const float* ps_u     = (const float*)d_in[5];
  const float* rs_u     = (const float*)d_in[6];
  const float* rw_u     = (const float*)d_in[7];
  const float* ps_m     = (const float*)d_in[8];
  const float* rs_m     = (const float*)d_in[9];
  const float* rw_m     = (const float*)d_in[10];
  const float* user_cj  = (const float*)d_in[11];
  const float* user_ci  = (const float*)d_in[12];
  const float* movie_cj = (const float*)d_in[13];
  const float* movie_ci = (const float*)d_in[14];
  const float* ufc_w    = (const float*)d_in[15];
  const float* ufc_b    = (const float*)d_in[16];
  const float* ifc_w    = (const float*)d_in[17];
  const float* ifc_b    = (const float*)d_in[18];

  float* out = (float*)d_out;

  // ---- workspace layout ----
  char* ws = (char*)d_ws;
  size_t o = 0;
  auto alloc = [&](size_t bytes) { char* p = ws + o; o += (bytes + 255) & ~(size_t)255; return p; };
  int*   cnt    = (int*)  alloc(sizeof(int) * NNODE);
  int*   off    = (int*)  alloc(sizeof(int) * NNODE);
  int*   cursor = (int*)  alloc(sizeof(int) * 1);
  int*   rank_m = (int*)  alloc(sizeof(int) * NE);
  int*   rank_u = (int*)  alloc(sizeof(int) * NE);
  short* msg    = (short*)alloc(sizeof(short) * (size_t)2 * NE * DD);   // 512 MB
  (void)ws_size;

  hipMemsetAsync(cnt, 0, sizeof(int) * NNODE, stream);
  hipMemsetAsync(cursor, 0, sizeof(int), stream);
  rank0_k<<<(NE / 4 + 255) / 256, 256, 0, stream>>>(edges_u, edges_m, cnt, rank_m, rank_u);
  scan_k<<<NCHUNK, 256, 0, stream>>>(cnt, cursor, off);

  dim3 g1((NTILE / 8 + 3) / 4, RR);   // (782, 5)
  gcmc_main<<<g1, 256, 0, stream>>>(edges_u, edges_m, rfeat, W_user, W_movie,
                                    ps_u, rs_u, rw_u, ps_m, rs_m, rw_m,
                                    user_cj, movie_cj, rank_m, rank_u, off, msg);

  gather_k<<<GM_BLOCKS + GU_BLOCKS, 256, 0, stream>>>(off, cnt, msg, out);

  gcmc_fc<<<(NNODE / 16) / 4, 256, 0, stream>>>(out, user_ci, movie_ci,
                                                ufc_w, ufc_b, ifc_w, ifc_b);
}

// Round 17
// 697.060 us; speedup vs baseline: 1.0229x; 1.0210x over previous
//
#include <hip/hip_runtime.h>
#include <hip/hip_bf16.h>

#define NU 100000
#define NM 20000
#define DD 64
#define RR 5
#define EE 400000
#define NE (RR * EE)            // 2,000,000 edges per direction
#define NNODE (NM + NU)         // 120,000 destination bins (movies first)
#define NTILE (EE / 16)         // 25,000 16-edge tiles per relation
#define NCHUNK ((NNODE + 1023) / 1024)   // 118 scan chunks
#define MFB (NM / 16)           // 1250 movie gather+fc blocks (16 movies/block)
#define UFB (NU / 32)           // 3125 user gather+fc blocks (32 users/block)

typedef __attribute__((ext_vector_type(8))) short bf16x8;
typedef __attribute__((ext_vector_type(8))) short s16x8;
typedef __attribute__((ext_vector_type(4))) int   i32x4;
typedef __attribute__((ext_vector_type(4))) float f32x4;

static __device__ __forceinline__ short f2bf(float f) {
  return __builtin_bit_cast(short, __float2bfloat16(f));
}
static __device__ __forceinline__ float bf2f(short s) {
  return __builtin_bit_cast(float, ((unsigned)(unsigned short)s) << 16);
}

// nt LOAD of host-written, read-once input only (rfeat). R14 lesson: nt
// STORES consumed by a later kernel corrupt data on gfx950 — never again.
static __device__ __forceinline__ f32x4 ntl_f4(const float* __restrict__ p) {
  return __builtin_nontemporal_load((const f32x4*)p);
}

static __device__ __forceinline__ bf16x8 pack8e(const f32x4 a, const f32x4 b) {
  bf16x8 o;
  o[0] = f2bf(a.x); o[1] = f2bf(a.y); o[2] = f2bf(a.z); o[3] = f2bf(a.w);
  o[4] = f2bf(b.x); o[5] = f2bf(b.y); o[6] = f2bf(b.z); o[7] = f2bf(b.w);
  return o;
}
static __device__ __forceinline__ bf16x8 cvt8(const float* __restrict__ p) {
  return pack8e(*(const f32x4*)p, *(const f32x4*)(p + 4));
}

static __device__ __forceinline__ float sigm(float x) { return 1.f / (1.f + __expf(-x)); }
static __device__ __forceinline__ float gelu(float x) {
  return 0.5f * x * (1.f + erff(x * 0.70710678118654752f));
}

// ---------------------------------------------------------------------------
// rank0: ONE atomic pass. cnt (zeroed) -> per-edge rank within destination,
// and cnt ends up holding the per-node degree.
// ---------------------------------------------------------------------------
__global__ __launch_bounds__(256) void rank0_k(const int* __restrict__ eu,
                                               const int* __restrict__ em,
                                               int* __restrict__ cnt,
                                               int* __restrict__ rank_m,
                                               int* __restrict__ rank_u) {
  const int i = (blockIdx.x * 256 + threadIdx.x) * 4;
  if (i < NE) {
    const i32x4 a = *(const i32x4*)(em + i);
    const i32x4 b = *(const i32x4*)(eu + i);
    i32x4 rm, ru;
    rm.x = atomicAdd(&cnt[a.x], 1);
    rm.y = atomicAdd(&cnt[a.y], 1);
    rm.z = atomicAdd(&cnt[a.z], 1);
    rm.w = atomicAdd(&cnt[a.w], 1);
    ru.x = atomicAdd(&cnt[NM + b.x], 1);
    ru.y = atomicAdd(&cnt[NM + b.y], 1);
    ru.z = atomicAdd(&cnt[NM + b.z], 1);
    ru.w = atomicAdd(&cnt[NM + b.w], 1);
    *(i32x4*)(rank_m + i) = rm;
    *(i32x4*)(rank_u + i) = ru;
  }
}

// ---------------------------------------------------------------------------
// ONE-dispatch scan: off need not be globally ordered, only disjoint with
// per-node contiguity — main uses off[dst]+rank, gather uses len=cnt[w].
// ---------------------------------------------------------------------------
__global__ __launch_bounds__(256) void scan_k(const int* __restrict__ cnt,
                                              int* __restrict__ cursor,
                                              int* __restrict__ off) {
  const int b = blockIdx.x;
  const int t = threadIdx.x;
  const int idx = b * 1024 + t * 4;
  i32x4 v = {0, 0, 0, 0};
  if (idx + 3 < NNODE) v = *(const i32x4*)(cnt + idx);
  else {
    if (idx     < NNODE) v.x = cnt[idx];
    if (idx + 1 < NNODE) v.y = cnt[idx + 1];
    if (idx + 2 < NNODE) v.z = cnt[idx + 2];
    if (idx + 3 < NNODE) v.w = cnt[idx + 3];
  }
  const int s = v.x + v.y + v.z + v.w;
  __shared__ int sh[256];
  __shared__ int base_sh;
  sh[t] = s;
  __syncthreads();
  for (int d = 1; d < 256; d <<= 1) {
    const int x = (t >= d) ? sh[t - d] : 0;
    __syncthreads();
    sh[t] += x;
    __syncthreads();
  }
  if (t == 255) base_sh = atomicAdd(cursor, sh[255]);
  __syncthreads();
  const int pre = base_sh + sh[t] - s;
  i32x4 o;
  o.x = pre;
  o.y = pre + v.x;
  o.z = pre + v.x + v.y;
  o.w = pre + v.x + v.y + v.z;
  if (idx + 3 < NNODE) *(i32x4*)(off + idx) = o;
  else {
    if (idx     < NNODE) off[idx]     = o.x;
    if (idx + 1 < NNODE) off[idx + 1] = o.y;
    if (idx + 2 < NNODE) off[idx + 2] = o.z;
    if (idx + 3 < NNODE) off[idx + 3] = o.w;
  }
}

// ---------------------------------------------------------------------------
// Main fused MFMA kernel — flat schedule, single dispatch (best measured).
// rfeat loads non-temporal (read-once stream; keeps W tables L3-resident).
// All stores plain (R14).  No min-waves clamp (R9: VGPR clamp -> spills).
// ---------------------------------------------------------------------------
__global__ __launch_bounds__(256) void gcmc_main(
    const int* __restrict__ edges_u, const int* __restrict__ edges_m,
    const float* __restrict__ rfeat,
    const float* __restrict__ W_user, const float* __restrict__ W_movie,
    const float* __restrict__ ps_u, const float* __restrict__ rs_u, const float* __restrict__ rw_u,
    const float* __restrict__ ps_m, const float* __restrict__ rs_m, const float* __restrict__ rw_m,
    const float* __restrict__ user_cj, const float* __restrict__ movie_cj,
    const int* __restrict__ rank_m, const int* __restrict__ rank_u,
    const int* __restrict__ off,
    short* __restrict__ msg)
{
  const int r    = blockIdx.y;
  const int lane = threadIdx.x & 63;
  const int wid  = threadIdx.x >> 6;
  const int c    = lane & 15;
  const int kr   = lane >> 4;
  const int wtile = blockIdx.x * 4 + wid;
  if (wtile >= NTILE / 8) return;

  bf16x8 Bu[4][2], Bm[4][2], Bs[2];
#pragma unroll
  for (int t = 0; t < 4; ++t) {
#pragma unroll
    for (int s = 0; s < 2; ++s) {
      Bu[t][s] = cvt8(rw_u + ((size_t)r * DD + (4 * c + t)) * DD + s * 32 + kr * 8);
      Bm[t][s] = cvt8(rw_m + ((size_t)r * DD + (4 * c + t)) * DD + s * 32 + kr * 8);
    }
  }
#pragma unroll
  for (int s = 0; s < 2; ++s) {
    if (c < 4) {
      const float* v = (c == 0 ? rs_u : c == 1 ? ps_u : c == 2 ? rs_m : ps_m)
                       + r * DD + s * 32 + kr * 8;
      Bs[s] = cvt8(v);
    } else {
      bf16x8 z = {0, 0, 0, 0, 0, 0, 0, 0};
      Bs[s] = z;
    }
  }

#pragma unroll 1
  for (int tt = 0; tt < 8; ++tt) {
    const int tile = wtile * 8 + tt;
    const int e0 = tile * 16;

    const float* arow = rfeat + ((size_t)r * EE + e0 + c) * DD + kr * 8;
    const f32x4 fa0 = ntl_f4(arow);
    const f32x4 fa1 = ntl_f4(arow + 4);
    const f32x4 fa2 = ntl_f4(arow + 32);
    const f32x4 fa3 = ntl_f4(arow + 36);

    const int ebase = r * EE + e0 + kr * 4;
    const i32x4 eu4  = *(const i32x4*)(edges_u + ebase);
    const i32x4 em4  = *(const i32x4*)(edges_m + ebase);
    const i32x4 rm4  = *(const i32x4*)(rank_m + ebase);
    const i32x4 ru4  = *(const i32x4*)(rank_u + ebase);
    const int eus[4] = {eu4.x, eu4.y, eu4.z, eu4.w};
    const int ems[4] = {em4.x, em4.y, em4.z, em4.w};
    const int rms[4] = {rm4.x, rm4.y, rm4.z, rm4.w};
    const int rus[4] = {ru4.x, ru4.y, ru4.z, ru4.w};

    int slm[4], slu[4];
    float cju[4], cjm[4];
    f32x4 hu[4], hm[4];
#pragma unroll
    for (int q = 0; q < 4; ++q) {
      slm[q] = off[ems[q]] + rms[q];
      slu[q] = off[NM + eus[q]] + rus[q];
      cju[q] = user_cj[eus[q]];
      cjm[q] = movie_cj[ems[q]];
      hu[q]  = *(const f32x4*)(W_user  + ((size_t)r * NU + eus[q]) * DD + 4 * c);
      hm[q]  = *(const f32x4*)(W_movie + ((size_t)r * NM + ems[q]) * DD + 4 * c);
    }

    const bf16x8 A0 = pack8e(fa0, fa1);
    const bf16x8 A1 = pack8e(fa2, fa3);
    f32x4 z4 = {0.f, 0.f, 0.f, 0.f};
    f32x4 Cu[4], Cm[4], Cs;
#pragma unroll
    for (int t = 0; t < 4; ++t) { Cu[t] = z4; Cm[t] = z4; }
    Cs = z4;
#pragma unroll
    for (int t = 0; t < 4; ++t) {
      Cu[t] = __builtin_amdgcn_mfma_f32_16x16x32_bf16(A0, Bu[t][0], Cu[t], 0, 0, 0);
      Cu[t] = __builtin_amdgcn_mfma_f32_16x16x32_bf16(A1, Bu[t][1], Cu[t], 0, 0, 0);
      Cm[t] = __builtin_amdgcn_mfma_f32_16x16x32_bf16(A0, Bm[t][0], Cm[t], 0, 0, 0);
      Cm[t] = __builtin_amdgcn_mfma_f32_16x16x32_bf16(A1, Bm[t][1], Cm[t], 0, 0, 0);
    }
    Cs = __builtin_amdgcn_mfma_f32_16x16x32_bf16(A0, Bs[0], Cs, 0, 0, 0);
    Cs = __builtin_amdgcn_mfma_f32_16x16x32_bf16(A1, Bs[1], Cs, 0, 0, 0);

#pragma unroll
    for (int q = 0; q < 4; ++q) {
      const int src = (lane & 48);
      const float su = __shfl(Cs[q], src);
      const float pu = __shfl(Cs[q], src | 1);
      const float sm = __shfl(Cs[q], src | 2);
      const float pm = __shfl(Cs[q], src | 3);
      const float sgu = sigm(su), pau = sigm(pu);
      const float sgm_ = sigm(sm), pam = sigm(pm);

      short4 vm, vu;
      vm.x = f2bf((hu[q].x * pau + Cu[0][q] * sgu) * cju[q]);
      vm.y = f2bf((hu[q].y * pau + Cu[1][q] * sgu) * cju[q]);
      vm.z = f2bf((hu[q].z * pau + Cu[2][q] * sgu) * cju[q]);
      vm.w = f2bf((hu[q].w * pau + Cu[3][q] * sgu) * cju[q]);
      vu.x = f2bf((hm[q].x * pam + Cm[0][q] * sgm_) * cjm[q]);
      vu.y = f2bf((hm[q].y * pam + Cm[1][q] * sgm_) * cjm[q]);
      vu.z = f2bf((hm[q].z * pam + Cm[2][q] * sgm_) * cjm[q]);
      vu.w = f2bf((hm[q].w * pam + Cm[3][q] * sgm_) * cjm[q]);

      *(short4*)(msg + ((size_t)slm[q] << 6) + 4 * c) = vm;
      *(short4*)(msg + ((size_t)slu[q] << 6) + 4 * c) = vu;
    }
  }
}

// ---------------------------------------------------------------------------
// fc tile on 16 LDS rows: dst[row][4c+t] = gelu(rows[row]*ci) @ W.T + b.
// Same math/layout as the old standalone fc kernel (agg passes via LDS fp32
// instead of HBM fp32 -> bitwise-identical numerics).
// ---------------------------------------------------------------------------
static __device__ __forceinline__ void fc_tile16(
    const float (*rows)[68], const float* __restrict__ ci,
    const float* __restrict__ W, const float* __restrict__ bias,
    float* __restrict__ dst, const int lane)
{
  const int c  = lane & 15;
  const int kr = lane >> 4;

  bf16x8 B[4][2];
#pragma unroll
  for (int t = 0; t < 4; ++t)
#pragma unroll
    for (int s = 0; s < 2; ++s)
      B[t][s] = cvt8(W + (size_t)(4 * c + t) * DD + s * 32 + kr * 8);

  const float civ = ci[c];
  bf16x8 A0, A1;
#pragma unroll
  for (int j = 0; j < 8; ++j) {
    A0[j] = f2bf(gelu(rows[c][kr * 8 + j] * civ));
    A1[j] = f2bf(gelu(rows[c][32 + kr * 8 + j] * civ));
  }

  f32x4 z4 = {0.f, 0.f, 0.f, 0.f};
  f32x4 C[4];
#pragma unroll
  for (int t = 0; t < 4; ++t) {
    C[t] = z4;
    C[t] = __builtin_amdgcn_mfma_f32_16x16x32_bf16(A0, B[t][0], C[t], 0, 0, 0);
    C[t] = __builtin_amdgcn_mfma_f32_16x16x32_bf16(A1, B[t][1], C[t], 0, 0, 0);
  }

  const f32x4 b4 = *(const f32x4*)(bias + 4 * c);
#pragma unroll
  for (int q = 0; q < 4; ++q) {
    f32x4 o;
    o.x = C[0][q] + b4.x; o.y = C[1][q] + b4.y;
    o.z = C[2][q] + b4.z; o.w = C[3][q] + b4.w;
    *(f32x4*)(dst + (size_t)(kr * 4 + q) * DD + 4 * c) = o;
  }
}

// ---------------------------------------------------------------------------
// Fused gather-reduce + fc (one dispatch, replaces gather_k and gcmc_fc).
//  blocks [0, MFB): 16 movies/block — each wave reduces 4 movies (full-wave
//    segment sum as before), rows staged in LDS, wave 0 runs the fc tile.
//  blocks [MFB, +UFB): 32 users/block — 8 lanes/user reduce, rows staged in
//    LDS, waves 0-1 run the two fc tiles.
// LDS rows padded to 68 floats to spread banks.
// ---------------------------------------------------------------------------
__global__ __launch_bounds__(256) void gather_fc_k(
    const int* __restrict__ off, const int* __restrict__ cnt,
    const short* __restrict__ msg,
    const float* __restrict__ user_ci, const float* __restrict__ movie_ci,
    const float* __restrict__ ufc_w, const float* __restrict__ ufc_b,
    const float* __restrict__ ifc_w, const float* __restrict__ ifc_b,
    float* __restrict__ out)
{
  __shared__ float rows[32][68];
  const int wid  = threadIdx.x >> 6;
  const int lane = threadIdx.x & 63;

  if (blockIdx.x < MFB) {
    const int mblk = blockIdx.x;
    const int sub  = lane >> 3;    // row group 0..7
    const int c8   = lane & 7;     // 16-byte chunk

#pragma unroll 1
    for (int mm = 0; mm < 4; ++mm) {
      const int mlocal = wid * 4 + mm;
      const int w = mblk * 16 + mlocal;
      const int s0 = off[w];
      const int e1 = s0 + cnt[w];

      float a0[8] = {0,0,0,0,0,0,0,0};
      float a1[8] = {0,0,0,0,0,0,0,0};
      float a2[8] = {0,0,0,0,0,0,0,0};
      float a3[8] = {0,0,0,0,0,0,0,0};
      int k = s0 + sub;
      for (; k + 24 < e1; k += 32) {
        const s16x8 v0 = *(const s16x8*)(msg + ((size_t)k << 6) + 8 * c8);
        const s16x8 v1 = *(const s16x8*)(msg + ((size_t)(k + 8) << 6) + 8 * c8);
        const s16x8 v2 = *(const s16x8*)(msg + ((size_t)(k + 16) << 6) + 8 * c8);
        const s16x8 v3 = *(const s16x8*)(msg + ((size_t)(k + 24) << 6) + 8 * c8);
#pragma unroll
        for (int j = 0; j < 8; ++j) {
          a0[j] += bf2f(v0[j]); a1[j] += bf2f(v1[j]);
          a2[j] += bf2f(v2[j]); a3[j] += bf2f(v3[j]);
        }
      }
      for (; k < e1; k += 8) {
        const s16x8 v0 = *(const s16x8*)(msg + ((size_t)k << 6) + 8 * c8);
#pragma unroll
        for (int j = 0; j < 8; ++j) a0[j] += bf2f(v0[j]);
      }
#pragma unroll
      for (int j = 0; j < 8; ++j) {
        a0[j] += a1[j] + a2[j] + a3[j];
        a0[j] += __shfl_xor(a0[j], 8);
        a0[j] += __shfl_xor(a0[j], 16);
        a0[j] += __shfl_xor(a0[j], 32);
      }
      if (sub == 0) {
#pragma unroll
        for (int j = 0; j < 8; ++j) rows[mlocal][8 * c8 + j] = a0[j];
      }
    }
    __syncthreads();
    if (wid == 0)
      fc_tile16(rows, movie_ci + mblk * 16, ifc_w, ifc_b,
                out + (size_t)NU * DD + (size_t)mblk * 16 * DD, lane);
  } else {
    const int ublk = blockIdx.x - MFB;
    const int ul   = threadIdx.x >> 3;   // local user 0..31
    const int c8   = threadIdx.x & 7;
    const int u    = ublk * 32 + ul;

    const int s0 = off[NM + u];
    const int e1 = s0 + cnt[NM + u];

    float a0[8] = {0,0,0,0,0,0,0,0};
    float a1[8] = {0,0,0,0,0,0,0,0};
    float a2[8] = {0,0,0,0,0,0,0,0};
    float a3[8] = {0,0,0,0,0,0,0,0};
    int k = s0;
    for (; k + 3 < e1; k += 4) {
      const s16x8 v0 = *(const s16x8*)(msg + ((size_t)k << 6) + 8 * c8);
      const s16x8 v1 = *(const s16x8*)(msg + ((size_t)(k + 1) << 6) + 8 * c8);
      const s16x8 v2 = *(const s16x8*)(msg + ((size_t)(k + 2) << 6) + 8 * c8);
      const s16x8 v3 = *(const s16x8*)(msg + ((size_t)(k + 3) << 6) + 8 * c8);
#pragma unroll
      for (int j = 0; j < 8; ++j) {
        a0[j] += bf2f(v0[j]); a1[j] += bf2f(v1[j]);
        a2[j] += bf2f(v2[j]); a3[j] += bf2f(v3[j]);
      }
    }
    for (; k < e1; ++k) {
      const s16x8 v0 = *(const s16x8*)(msg + ((size_t)k << 6) + 8 * c8);
#pragma unroll
      for (int j = 0; j < 8; ++j) a0[j] += bf2f(v0[j]);
    }
#pragma unroll
    for (int j = 0; j < 8; ++j) rows[ul][8 * c8 + j] = a0[j] + a1[j] + a2[j] + a3[j];

    __syncthreads();
    if (wid < 2)
      fc_tile16(rows + wid * 16, user_ci + ublk * 32 + wid * 16, ufc_w, ufc_b,
                out + (size_t)(ublk * 32 + wid * 16) * DD, lane);
  }
}

extern "C" void kernel_launch(void* const* d_in, const int* in_sizes, int n_in,
                              void* d_out, int out_size, void* d_ws, size_t ws_size,
                              hipStream_t stream) {
  const int*   edges_u  = (const int*)  d_in[0];
  const int*   edges_m  = (const int*)  d_in[1];
  const float* rfeat    = (const float*)d_in[2];
  const float* W_user   = (const float*)d_in[3];
  const float* W_movie  = (const float*)d_in[4];
  const float* ps_u     = (const float*)d_in[5];
  const float* rs_u     = (const float*)d_in[6];
  const float* rw_u     = (const float*)d_in[7];
  const float* ps_m     = (const float*)d_in[8];
  const float* rs_m     = (const float*)d_in[9];
  const float* rw_m     = (const float*)d_in[10];
  const float* user_cj  = (const float*)d_in[11];
  const float* user_ci  = (const float*)d_in[12];
  const float* movie_cj = (const float*)d_in[13];
  const float* movie_ci = (const float*)d_in[14];
  const float* ufc_w    = (const float*)d_in[15];
  const float* ufc_b    = (const float*)d_in[16];
  const float* ifc_w    = (const float*)d_in[17];
  const float* ifc_b    = (const float*)d_in[18];

  float* out = (float*)d_out;

  // ---- workspace layout ----
  char* ws = (char*)d_ws;
  size_t o = 0;
  auto alloc = [&](size_t bytes) { char* p = ws + o; o += (bytes + 255) & ~(size_t)255; return p; };
  int*   cnt    = (int*)  alloc(sizeof(int) * NNODE);
  int*   off    = (int*)  alloc(sizeof(int) * NNODE);
  int*   cursor = (int*)  alloc(sizeof(int) * 1);
  int*   rank_m = (int*)  alloc(sizeof(int) * NE);
  int*   rank_u = (int*)  alloc(sizeof(int) * NE);
  short* msg    = (short*)alloc(sizeof(short) * (size_t)2 * NE * DD);   // 512 MB
  (void)ws_size;

  hipMemsetAsync(cnt, 0, sizeof(int) * NNODE, stream);
  hipMemsetAsync(cursor, 0, sizeof(int), stream);
  rank0_k<<<(NE / 4 + 255) / 256, 256, 0, stream>>>(edges_u, edges_m, cnt, rank_m, rank_u);
  scan_k<<<NCHUNK, 256, 0, stream>>>(cnt, cursor, off);

  dim3 g1((NTILE / 8 + 3) / 4, RR);   // (782, 5)
  gcmc_main<<<g1, 256, 0, stream>>>(edges_u, edges_m, rfeat, W_user, W_movie,
                                    ps_u, rs_u, rw_u, ps_m, rs_m, rw_m,
                                    user_cj, movie_cj, rank_m, rank_u, off, msg);

  gather_fc_k<<<MFB + UFB, 256, 0, stream>>>(off, cnt, msg,
                                             user_ci, movie_ci,
                                             ufc_w, ufc_b, ifc_w, ifc_b, out);
}